// Round 1
// baseline (1153.722 us; speedup 1.0000x reference)
//
#include <hip/hip_runtime.h>
#include <math.h>

// Problem constants (x: [4096,4096] f32, codebook: [256,4096] f32)
#define D_DIM   4096
#define B_ROWS  4096
#define K_CODES 256
#define N_CHUNK 4              // D split into 4 chunks of 1024
#define D_CHUNK (D_DIM / N_CHUNK)
#define M_TILE  64
#define LDX     36             // padded LDS leading dim (floats)

// output layout (elements, f32)
#define IDX_OFF   (B_ROWS * D_DIM)                 // 16777216
#define PROBS_OFF (IDX_OFF + B_ROWS)               // 16781312
#define LOSS_OFF  (PROBS_OFF + B_ROWS * K_CODES)   // 17829888

// ---------------------------------------------------------------------------
// Kernel 1: exact-ish f64 codebook squared norms cc[k] = sum_d cb[k][d]^2
// ---------------------------------------------------------------------------
__global__ __launch_bounds__(256) void cc_kernel(const float* __restrict__ cb,
                                                 double* __restrict__ cc) {
    __shared__ double red[256];
    const int k = blockIdx.x, t = threadIdx.x;
    const float* row = cb + (size_t)k * D_DIM;
    double s = 0.0;
    for (int d = t; d < D_DIM; d += 256) { double v = row[d]; s += v * v; }
    red[t] = s; __syncthreads();
    for (int off = 128; off > 0; off >>= 1) {
        if (t < off) red[t] += red[t + off];
        __syncthreads();
    }
    if (t == 0) cc[k] = red[0];
}

// ---------------------------------------------------------------------------
// Kernel 2: partial GEMM  G[m][k] = sum_{d in chunk} x[m][d]*cb[k][d]  (f32)
// Block: 256 threads = 8 m-groups x 32 k-groups; per-thread 8x8 register tile.
// Grid: (B_ROWS/M_TILE, N_CHUNK) = (64, 4) = 256 blocks.
// ---------------------------------------------------------------------------
__global__ __launch_bounds__(256) void gemm_partial(const float* __restrict__ x,
                                                    const float* __restrict__ cb,
                                                    float* __restrict__ part) {
    __shared__ float xs[M_TILE][LDX];    // 64 x 36 floats  (9 KB)
    __shared__ float cs[K_CODES][LDX];   // 256 x 36 floats (36 KB)
    const int t  = threadIdx.x;
    const int km = t & 31;               // k-group: covers k = km + 32*j
    const int mg = t >> 5;               // m-group: covers m = mg*8 + i
    const int m0 = blockIdx.x * M_TILE;
    const int chunk = blockIdx.y;
    const int gd_base = chunk * D_CHUNK;

    float acc[8][8];
#pragma unroll
    for (int i = 0; i < 8; ++i)
#pragma unroll
        for (int j = 0; j < 8; ++j) acc[i][j] = 0.f;

    for (int d0 = 0; d0 < D_CHUNK; d0 += 32) {
        const int gd = gd_base + d0;
        // global -> regs (issued before the sync for overlap)
        float4 xr[2], cr[8];
#pragma unroll
        for (int r = 0; r < 2; ++r) {
            const int idx = t + 256 * r, row = idx >> 3, q = idx & 7;
            xr[r] = *(const float4*)(x + (size_t)(m0 + row) * D_DIM + gd + q * 4);
        }
#pragma unroll
        for (int r = 0; r < 8; ++r) {
            const int idx = t + 256 * r, row = idx >> 3, q = idx & 7;
            cr[r] = *(const float4*)(cb + (size_t)row * D_DIM + gd + q * 4);
        }
        __syncthreads();   // previous stage's compute done
#pragma unroll
        for (int r = 0; r < 2; ++r) {
            const int idx = t + 256 * r, row = idx >> 3, q = idx & 7;
            *(float4*)&xs[row][q * 4] = xr[r];
        }
#pragma unroll
        for (int r = 0; r < 8; ++r) {
            const int idx = t + 256 * r, row = idx >> 3, q = idx & 7;
            *(float4*)&cs[row][q * 4] = cr[r];
        }
        __syncthreads();
#pragma unroll
        for (int dq = 0; dq < 8; ++dq) {
            float4 a[8], b[8];
#pragma unroll
            for (int i = 0; i < 8; ++i) a[i] = *(const float4*)&xs[mg * 8 + i][dq * 4];
#pragma unroll
            for (int j = 0; j < 8; ++j) b[j] = *(const float4*)&cs[km + 32 * j][dq * 4];
#pragma unroll
            for (int i = 0; i < 8; ++i)
#pragma unroll
                for (int j = 0; j < 8; ++j)
                    acc[i][j] += a[i].x * b[j].x + a[i].y * b[j].y
                               + a[i].z * b[j].z + a[i].w * b[j].w;
        }
    }
    // write partials: part[chunk][m][k], coalesced over km
#pragma unroll
    for (int i = 0; i < 8; ++i) {
        const int m = m0 + mg * 8 + i;
        float* dst = part + ((size_t)chunk * B_ROWS + m) * K_CODES;
#pragma unroll
        for (int j = 0; j < 8; ++j) dst[km + 32 * j] = acc[i][j];
    }
}

// ---------------------------------------------------------------------------
// Kernel 3: per-row epilogue. One block per row, 256 threads (thread t <-> k).
//  - xx = ||x_row||^2 in f64
//  - d2[k] = xx + cc[k] - 2*G[k]  (G from f32 partials, summed in f64)
//  - candidates within 0.25 of max get an exact f64 dot refinement
//  - argmax (first occurrence) -> indices, quant gather, loss; probs = 0
// ---------------------------------------------------------------------------
__global__ __launch_bounds__(256) void epilogue(const float* __restrict__ x,
                                                const float* __restrict__ cb,
                                                const float* __restrict__ part,
                                                const double* __restrict__ cc,
                                                float* __restrict__ out) {
    __shared__ double red[256];
    __shared__ double vals[K_CODES];
    const int row = blockIdx.x, t = threadIdx.x;
    const float* xrow = x + (size_t)row * D_DIM;

    // xx (f64)
    double s = 0.0;
    for (int d = t; d < D_DIM; d += 256) { double v = xrow[d]; s += v * v; }
    red[t] = s; __syncthreads();
    for (int off = 128; off > 0; off >>= 1) {
        if (t < off) red[t] += red[t + off];
        __syncthreads();
    }
    const double xx = red[0];
    __syncthreads();

    // approx d2 for k = t
    double G = 0.0;
    for (int c = 0; c < N_CHUNK; ++c)
        G += (double)part[((size_t)c * B_ROWS + row) * K_CODES + t];
    vals[t] = xx + cc[t] - 2.0 * G;
    __syncthreads();

    // block-uniform scan for max (LDS broadcast reads)
    double mx = -1e300;
    for (int k = 0; k < K_CODES; ++k) { double v = vals[k]; if (v > mx) mx = v; }

    // refine candidates in exact f64; strict '>' keeps first occurrence
    double best = -1e300; int bestk = 0;
    for (int k = 0; k < K_CODES; ++k) {
        if (vals[k] >= mx - 0.25) {   // uniform condition -> sync-safe
            const float* crow = cb + (size_t)k * D_DIM;
            double sd = 0.0;
            for (int d = t; d < D_DIM; d += 256)
                sd += (double)xrow[d] * (double)crow[d];
            __syncthreads();
            red[t] = sd; __syncthreads();
            for (int off = 128; off > 0; off >>= 1) {
                if (t < off) red[t] += red[t + off];
                __syncthreads();
            }
            const double d2e = xx + cc[k] - 2.0 * red[0];
            __syncthreads();
            if (d2e > best) { best = d2e; bestk = k; }
        }
    }

    // probs: true value ~ normed * 2^-988 -> 0.0f in f32
    out[PROBS_OFF + (size_t)row * K_CODES + t] = 0.0f;
    if (t == 0) {
        out[IDX_OFF + row]  = (float)bestk;
        out[LOSS_OFF + row] = (float)(1.25 * best / (double)D_DIM);
    }
    // quant = codebook[bestk] (bestk uniform across block)
    const float4* src = (const float4*)(cb + (size_t)bestk * D_DIM);
    float4* dst = (float4*)(out + (size_t)row * D_DIM);
    for (int q = t; q < D_DIM / 4; q += 256) dst[q] = src[q];
}

// ---------------------------------------------------------------------------
extern "C" void kernel_launch(void* const* d_in, const int* in_sizes, int n_in,
                              void* d_out, int out_size, void* d_ws, size_t ws_size,
                              hipStream_t stream) {
    const float* x  = (const float*)d_in[0];
    const float* cb = (const float*)d_in[1];
    float* out = (float*)d_out;
    // ws: [N_CHUNK][B_ROWS][K_CODES] f32 partials (16 MB) + cc[256] f64
    float*  part = (float*)d_ws;
    double* cc   = (double*)((char*)d_ws + (size_t)N_CHUNK * B_ROWS * K_CODES * sizeof(float));

    hipLaunchKernelGGL(cc_kernel, dim3(K_CODES), dim3(256), 0, stream, cb, cc);
    hipLaunchKernelGGL(gemm_partial, dim3(B_ROWS / M_TILE, N_CHUNK), dim3(256), 0, stream,
                       x, cb, part);
    hipLaunchKernelGGL(epilogue, dim3(B_ROWS), dim3(256), 0, stream, x, cb, part, cc, out);
}

// Round 2
// 241.283 us; speedup vs baseline: 4.7816x; 4.7816x over previous
//
#include <hip/hip_runtime.h>
#include <hip/hip_bf16.h>
#include <math.h>

#define D_DIM   4096
#define B_ROWS  4096
#define K_CODES 256
#define MARGIN  3.0      // bf16-GEMM d2 error is <=~1.1 worst-case; 3.0 is ~10 sigma

// output layout (f32 elements)
#define IDX_OFF   (B_ROWS * D_DIM)                 // 16777216
#define PROBS_OFF (IDX_OFF + B_ROWS)               // 16781312
#define LOSS_OFF  (PROBS_OFF + B_ROWS * K_CODES)   // 17829888

typedef __bf16 bf16x8 __attribute__((ext_vector_type(8)));
typedef float  f32x16 __attribute__((ext_vector_type(16)));

// workspace layout (bytes): part[2][4096][256] f32 (8 MB) | cb_bf16[256][4096] u16 (2 MB)
//                           | cc[256] f64 | xx[4096] f64
#define PART_ELEMS ((size_t)2 * B_ROWS * K_CODES)

static __device__ inline unsigned short f2bf(float f) {
    __hip_bfloat16 h = __float2bfloat16(f);
    return *reinterpret_cast<unsigned short*>(&h);
}

// ---------------------------------------------------------------------------
// prep: wave-per-row, shuffle-only.
//   rows 0..4095   : xx[row] = ||x_row||^2 (f64); zero probs row
//   rows 4096..4351: cb row -> bf16; cc[k] = ||cb_k||^2 (f64)
// ---------------------------------------------------------------------------
__global__ __launch_bounds__(256) void prep(const float* __restrict__ x,
                                            const float* __restrict__ cb,
                                            unsigned short* __restrict__ cbh,
                                            double* __restrict__ cc,
                                            double* __restrict__ xx,
                                            float* __restrict__ out) {
    const int lane = threadIdx.x & 63;
    const int idx = blockIdx.x * 4 + (threadIdx.x >> 6);
    if (idx < B_ROWS) {
        const float4* row4 = (const float4*)(x + (size_t)idx * D_DIM);
        double s = 0.0;
#pragma unroll
        for (int i = 0; i < 16; ++i) {
            float4 v = row4[i * 64 + lane];
            s += (double)v.x * v.x + (double)v.y * v.y
               + (double)v.z * v.z + (double)v.w * v.w;
        }
        for (int off = 32; off; off >>= 1) s += __shfl_xor(s, off);
        if (lane == 0) xx[idx] = s;
        // zero probs row (64 lanes x float4 = 256 f32)
        float4 z = make_float4(0.f, 0.f, 0.f, 0.f);
        ((float4*)(out + PROBS_OFF + (size_t)idx * K_CODES))[lane] = z;
    } else {
        const int k = idx - B_ROWS;  // 0..255
        const float4* row4 = (const float4*)(cb + (size_t)k * D_DIM);
        ushort4* dst4 = (ushort4*)(cbh + (size_t)k * D_DIM);
        double s = 0.0;
#pragma unroll
        for (int i = 0; i < 16; ++i) {
            float4 v = row4[i * 64 + lane];
            s += (double)v.x * v.x + (double)v.y * v.y
               + (double)v.z * v.z + (double)v.w * v.w;
            ushort4 h;
            h.x = f2bf(v.x); h.y = f2bf(v.y); h.z = f2bf(v.z); h.w = f2bf(v.w);
            dst4[i * 64 + lane] = h;
        }
        for (int off = 32; off; off >>= 1) s += __shfl_xor(s, off);
        if (lane == 0) cc[k] = s;
    }
}

// ---------------------------------------------------------------------------
// gemm: wave-per-tile 32m x 64n, K-split 2 (K=2048/wave), mfma_f32_32x32x16_bf16.
// A: x f32 loaded + converted inline. B: pre-converted cb bf16 (L2-resident).
// 1024 waves = 256 blocks x 4 waves. Barrier-free (no LDS).
// Fragment layouts (learn_hip-verified family):
//   A: lane holds A[m = lane&31][k = 8*(lane>>5) + j], j=0..7 (contiguous k)
//   B: lane holds B[k = 8*(lane>>5) + j][n = lane&31]  (= cb[n][k], contiguous k)
//   C/D: col(n) = lane&31, row(m) = (reg&3) + 8*(reg>>2) + 4*(lane>>5)
// ---------------------------------------------------------------------------
__global__ __launch_bounds__(256) void gemm(const float* __restrict__ x,
                                            const unsigned short* __restrict__ cbh,
                                            float* __restrict__ part) {
    const int lane = threadIdx.x & 63;
    const int w = blockIdx.x * 4 + (threadIdx.x >> 6);   // 0..1023
    const int mt = w >> 3;            // 0..127
    const int ng = (w >> 1) & 3;      // 0..3
    const int ks = w & 1;             // 0..1
    const int m0 = mt * 32, n0 = ng * 64, k0 = ks * 2048;
    const int half = lane >> 5, mr = lane & 31;

    const float*          xp  = x   + (size_t)(m0 + mr) * D_DIM + k0 + half * 8;
    const unsigned short* b0p = cbh + (size_t)(n0 + mr) * D_DIM + k0 + half * 8;
    const unsigned short* b1p = b0p + (size_t)32 * D_DIM;

    f32x16 acc0, acc1;
#pragma unroll
    for (int i = 0; i < 16; ++i) { acc0[i] = 0.f; acc1[i] = 0.f; }

    for (int kk = 0; kk < 2048; kk += 16) {
        float4 a01 = *(const float4*)(xp);
        float4 a23 = *(const float4*)(xp + 4);
        bf16x8 af;
        af[0] = (__bf16)a01.x; af[1] = (__bf16)a01.y;
        af[2] = (__bf16)a01.z; af[3] = (__bf16)a01.w;
        af[4] = (__bf16)a23.x; af[5] = (__bf16)a23.y;
        af[6] = (__bf16)a23.z; af[7] = (__bf16)a23.w;
        bf16x8 bf0 = *(const bf16x8*)(b0p);
        bf16x8 bf1 = *(const bf16x8*)(b1p);
        acc0 = __builtin_amdgcn_mfma_f32_32x32x16_bf16(af, bf0, acc0, 0, 0, 0);
        acc1 = __builtin_amdgcn_mfma_f32_32x32x16_bf16(af, bf1, acc1, 0, 0, 0);
        xp += 16; b0p += 16; b1p += 16;
    }

    float* dst = part + (size_t)ks * B_ROWS * K_CODES + (size_t)m0 * K_CODES + n0;
#pragma unroll
    for (int r = 0; r < 16; ++r) {
        const int rowit = (r & 3) + 8 * (r >> 2) + 4 * half;
        dst[rowit * K_CODES + mr]      = acc0[r];
        dst[rowit * K_CODES + 32 + mr] = acc1[r];
    }
}

// ---------------------------------------------------------------------------
// epilogue: wave-per-row, shuffle-only, no LDS/barriers.
//   vals[k] = xx + cc[k] - 2*(part0+part1)[k]  (f64 from f32 partials)
//   butterfly max -> candidates within MARGIN -> exact f64 dot refinement
//   (ascending-k processing preserves first-occurrence tie-break)
// ---------------------------------------------------------------------------
__global__ __launch_bounds__(256) void epilogue(const float* __restrict__ x,
                                                const float* __restrict__ cb,
                                                const float* __restrict__ part,
                                                const double* __restrict__ cc,
                                                const double* __restrict__ xx,
                                                float* __restrict__ out) {
    const int lane = threadIdx.x & 63;
    const int row = blockIdx.x * 4 + (threadIdx.x >> 6);
    const float* xrow = x + (size_t)row * D_DIM;
    const double xxr = xx[row];

    float4 p0 = ((const float4*)(part + (size_t)row * K_CODES))[lane];
    float4 p1 = ((const float4*)(part + (size_t)B_ROWS * K_CODES + (size_t)row * K_CODES))[lane];
    double v[4];
    v[0] = xxr + cc[4 * lane + 0] - 2.0 * ((double)p0.x + (double)p1.x);
    v[1] = xxr + cc[4 * lane + 1] - 2.0 * ((double)p0.y + (double)p1.y);
    v[2] = xxr + cc[4 * lane + 2] - 2.0 * ((double)p0.z + (double)p1.z);
    v[3] = xxr + cc[4 * lane + 3] - 2.0 * ((double)p0.w + (double)p1.w);

    double mx = fmax(fmax(v[0], v[1]), fmax(v[2], v[3]));
    for (int off = 32; off; off >>= 1) mx = fmax(mx, __shfl_xor(mx, off));
    const double thr = mx - MARGIN;

    int flags = 0;
#pragma unroll
    for (int j = 0; j < 4; ++j) if (v[j] >= thr) flags |= 1 << j;
    unsigned long long cand = __ballot(flags != 0);

    double best = -1.0e300; int bestk = 0;
    while (cand) {
        const int lsrc = __builtin_ctzll(cand);
        cand &= cand - 1;
        const int f = __shfl(flags, lsrc);
        for (int j = 0; j < 4; ++j) {
            if (!((f >> j) & 1)) continue;
            const int k = 4 * lsrc + j;
            const float* crow = cb + (size_t)k * D_DIM;
            double s = 0.0;
            for (int d = lane; d < D_DIM; d += 64)
                s += (double)xrow[d] * (double)crow[d];
            for (int off = 32; off; off >>= 1) s += __shfl_xor(s, off);
            const double d2e = xxr + cc[k] - 2.0 * s;   // bit-identical across lanes
            if (d2e > best) { best = d2e; bestk = k; }  // strict > => first occurrence
        }
    }

    if (lane == 0) {
        out[IDX_OFF + row]  = (float)bestk;
        out[LOSS_OFF + row] = (float)(1.25 * best / (double)D_DIM);
    }
    // quant = codebook[bestk] (uniform across wave)
    const float4* src = (const float4*)(cb + (size_t)bestk * D_DIM);
    float4* dst = (float4*)(out + (size_t)row * D_DIM);
#pragma unroll
    for (int i = 0; i < 16; ++i) dst[i * 64 + lane] = src[i * 64 + lane];
}

// ---------------------------------------------------------------------------
extern "C" void kernel_launch(void* const* d_in, const int* in_sizes, int n_in,
                              void* d_out, int out_size, void* d_ws, size_t ws_size,
                              hipStream_t stream) {
    const float* x  = (const float*)d_in[0];
    const float* cb = (const float*)d_in[1];
    float* out = (float*)d_out;

    float*          part = (float*)d_ws;
    unsigned short* cbh  = (unsigned short*)((char*)d_ws + PART_ELEMS * sizeof(float));
    double*         cc   = (double*)((char*)cbh + (size_t)K_CODES * D_DIM * sizeof(unsigned short));
    double*         xx   = cc + K_CODES;

    hipLaunchKernelGGL(prep, dim3(1088), dim3(256), 0, stream, x, cb, cbh, cc, xx, out);
    hipLaunchKernelGGL(gemm, dim3(256), dim3(256), 0, stream, x, cbh, part);
    hipLaunchKernelGGL(epilogue, dim3(1024), dim3(256), 0, stream, x, cb, part, cc, xx, out);
}

// Round 3
// 169.913 us; speedup vs baseline: 6.7901x; 1.4200x over previous
//
#include <hip/hip_runtime.h>
#include <hip/hip_bf16.h>
#include <math.h>

#define D_DIM   4096
#define B_ROWS  4096
#define K_CODES 256
#define MARGIN  3.0      // bf16-GEMM d2 error <=~1.1 worst-case; 3.0 is ~10 sigma
#define KS      4        // K-split
#define KSLICE  (D_DIM / KS)   // 1024
#define BK      32
#define LDA     40       // A LDS row pad (bf16 elems): 80 B rows, 16B-aligned

// output layout (f32 elements)
#define IDX_OFF   (B_ROWS * D_DIM)                 // 16777216
#define PROBS_OFF (IDX_OFF + B_ROWS)               // 16781312
#define LOSS_OFF  (PROBS_OFF + B_ROWS * K_CODES)   // 17829888

typedef __bf16 bf16x8 __attribute__((ext_vector_type(8)));
typedef float  f32x16 __attribute__((ext_vector_type(16)));

// ws layout: part[KS][4096][256] f32 (16 MB) | cbh[256][4096] u16 (2 MB)
//            | cc[256] f64 | xx[4096] f64 | idxws[4096] i32
#define PART_ELEMS ((size_t)KS * B_ROWS * K_CODES)

static __device__ inline unsigned short f2bf(float f) {
    __hip_bfloat16 h = __float2bfloat16(f);
    return *reinterpret_cast<unsigned short*>(&h);
}

// ---------------------------------------------------------------------------
// prep: wave-per-row. rows 0..4095: xx (f64) + zero probs row.
//       rows 4096..4351: cb -> bf16, cc (f64).
// ---------------------------------------------------------------------------
__global__ __launch_bounds__(256) void prep(const float* __restrict__ x,
                                            const float* __restrict__ cb,
                                            unsigned short* __restrict__ cbh,
                                            double* __restrict__ cc,
                                            double* __restrict__ xx,
                                            float* __restrict__ out) {
    const int lane = threadIdx.x & 63;
    const int idx = blockIdx.x * 4 + (threadIdx.x >> 6);
    if (idx < B_ROWS) {
        const float4* row4 = (const float4*)(x + (size_t)idx * D_DIM);
        double a0 = 0.0, a1 = 0.0, a2 = 0.0, a3 = 0.0;
#pragma unroll
        for (int i = 0; i < 16; ++i) {
            float4 v = row4[i * 64 + lane];
            a0 += (double)v.x * v.x; a1 += (double)v.y * v.y;
            a2 += (double)v.z * v.z; a3 += (double)v.w * v.w;
        }
        double s = (a0 + a1) + (a2 + a3);
        for (int off = 32; off; off >>= 1) s += __shfl_xor(s, off);
        if (lane == 0) xx[idx] = s;
        float4 z = make_float4(0.f, 0.f, 0.f, 0.f);
        ((float4*)(out + PROBS_OFF + (size_t)idx * K_CODES))[lane] = z;
    } else {
        const int k = idx - B_ROWS;  // 0..255
        const float4* row4 = (const float4*)(cb + (size_t)k * D_DIM);
        ushort4* dst4 = (ushort4*)(cbh + (size_t)k * D_DIM);
        double a0 = 0.0, a1 = 0.0, a2 = 0.0, a3 = 0.0;
#pragma unroll
        for (int i = 0; i < 16; ++i) {
            float4 v = row4[i * 64 + lane];
            a0 += (double)v.x * v.x; a1 += (double)v.y * v.y;
            a2 += (double)v.z * v.z; a3 += (double)v.w * v.w;
            ushort4 h;
            h.x = f2bf(v.x); h.y = f2bf(v.y); h.z = f2bf(v.z); h.w = f2bf(v.w);
            dst4[i * 64 + lane] = h;
        }
        double s = (a0 + a1) + (a2 + a3);
        for (int off = 32; off; off >>= 1) s += __shfl_xor(s, off);
        if (lane == 0) cc[k] = s;
    }
}

// ---------------------------------------------------------------------------
// gemm: block = 32 rows x 256 codes x KSLICE. 4 waves, wave w owns codes
// w*64..w*64+63 (2 MFMA 32x32 subtiles), acc 32 VGPRs/wave.
// A: x f32 -> regs -> bf16 -> padded LDS.  B: cbh bf16 via global_load_lds.
// Fragment layouts identical to the round-2 verified kernel.
// ---------------------------------------------------------------------------
__global__ __launch_bounds__(256, 2) void gemm(const float* __restrict__ x,
                                               const unsigned short* __restrict__ cbh,
                                               float* __restrict__ part) {
    __shared__ unsigned short Ah[32 * LDA];       // 2.5 KB
    __shared__ unsigned short Bs[K_CODES * BK];   // 16 KB (order = load order!)
    const int t = threadIdx.x;
    const int lane = t & 63, w = t >> 6;
    const int half = lane >> 5, mr = lane & 31;
    const int m0 = blockIdx.x * 32;
    const int k0 = blockIdx.y * KSLICE;

    // A staging: thread t loads x[m0 + t/8][k0+kk + 4*(t%8) .. +3]
    const int ar = t >> 3, acq = (t & 7) * 4;
    const float* agp = x + (size_t)(m0 + ar) * D_DIM + k0 + acq;
    unsigned short* adst = &Ah[ar * LDA + acq];

    // B staging: chunk c = t + 256r -> cbh[c/4][k0+kk + 8*(c%4) .. +7], LDS elem c*8
    const unsigned short* bgp[4];
#pragma unroll
    for (int r = 0; r < 4; ++r) {
        const int c = t + 256 * r;
        bgp[r] = cbh + (size_t)(c >> 2) * D_DIM + k0 + 8 * (c & 3);
    }

    f32x16 acc0, acc1;
#pragma unroll
    for (int i = 0; i < 16; ++i) { acc0[i] = 0.f; acc1[i] = 0.f; }

    float4 av = *(const float4*)(agp);   // prefetch iter 0
    for (int kk = 0; kk < KSLICE; kk += BK) {
        const int kn = (kk + BK < KSLICE) ? kk + BK : 0;   // clamped (always valid)
        float4 av_next = *(const float4*)(agp + kn);
        __syncthreads();   // previous iter's LDS reads complete
#pragma unroll
        for (int r = 0; r < 4; ++r) {
            __builtin_amdgcn_global_load_lds(
                (const __attribute__((address_space(1))) void*)(bgp[r] + kk),
                (__attribute__((address_space(3))) void*)(&Bs[(t + 256 * r) * 8]),
                16, 0, 0);
        }
        ushort4 ah;
        ah.x = f2bf(av.x); ah.y = f2bf(av.y); ah.z = f2bf(av.z); ah.w = f2bf(av.w);
        *(ushort4*)adst = ah;
        __syncthreads();   // drains ds_write + global_load_lds (vmcnt) before use
#pragma unroll
        for (int s = 0; s < 2; ++s) {
            bf16x8 af = *(const bf16x8*)&Ah[mr * LDA + s * 16 + half * 8];
            bf16x8 b0 = *(const bf16x8*)&Bs[(w * 64 + mr) * BK + s * 16 + half * 8];
            bf16x8 b1 = *(const bf16x8*)&Bs[(w * 64 + 32 + mr) * BK + s * 16 + half * 8];
            acc0 = __builtin_amdgcn_mfma_f32_32x32x16_bf16(af, b0, acc0, 0, 0, 0);
            acc1 = __builtin_amdgcn_mfma_f32_32x32x16_bf16(af, b1, acc1, 0, 0, 0);
        }
        av = av_next;
    }
    // part[ks][row][code]; coalesced over mr
    float* dst = part + ((size_t)blockIdx.y * B_ROWS + m0) * K_CODES + w * 64;
#pragma unroll
    for (int r = 0; r < 16; ++r) {
        const int rowit = (r & 3) + 8 * (r >> 2) + 4 * half;
        dst[(size_t)rowit * K_CODES + mr]      = acc0[r];
        dst[(size_t)rowit * K_CODES + 32 + mr] = acc1[r];
    }
}

// ---------------------------------------------------------------------------
// refine: wave-per-row, shuffle-only. vals from KS partials (f64), butterfly
// max, candidates within MARGIN refined with an exact f64 dot (float4 loads,
// 4 independent accumulators -> no serial chain). Writes idx/loss only.
// ---------------------------------------------------------------------------
__global__ __launch_bounds__(256) void refine(const float* __restrict__ x,
                                              const float* __restrict__ cb,
                                              const float* __restrict__ part,
                                              const double* __restrict__ cc,
                                              const double* __restrict__ xx,
                                              float* __restrict__ out,
                                              int* __restrict__ idxws) {
    const int lane = threadIdx.x & 63;
    const int row = blockIdx.x * 4 + (threadIdx.x >> 6);
    const float4* xrow4 = (const float4*)(x + (size_t)row * D_DIM);
    const double xxr = xx[row];

    float4 p[KS];
#pragma unroll
    for (int s = 0; s < KS; ++s)
        p[s] = ((const float4*)(part + ((size_t)s * B_ROWS + row) * K_CODES))[lane];
    double v[4];
    v[0] = xxr + cc[4 * lane + 0] - 2.0 * (((double)p[0].x + p[1].x) + ((double)p[2].x + p[3].x));
    v[1] = xxr + cc[4 * lane + 1] - 2.0 * (((double)p[0].y + p[1].y) + ((double)p[2].y + p[3].y));
    v[2] = xxr + cc[4 * lane + 2] - 2.0 * (((double)p[0].z + p[1].z) + ((double)p[2].z + p[3].z));
    v[3] = xxr + cc[4 * lane + 3] - 2.0 * (((double)p[0].w + p[1].w) + ((double)p[2].w + p[3].w));

    double mx = fmax(fmax(v[0], v[1]), fmax(v[2], v[3]));
    for (int off = 32; off; off >>= 1) mx = fmax(mx, __shfl_xor(mx, off));
    const double thr = mx - MARGIN;

    int flags = 0;
#pragma unroll
    for (int j = 0; j < 4; ++j) if (v[j] >= thr) flags |= 1 << j;
    unsigned long long cand = __ballot(flags != 0);

    double best = -1.0e300; int bestk = 0;
    while (cand) {
        const int lsrc = __builtin_ctzll(cand);
        cand &= cand - 1;
        const int f = __shfl(flags, lsrc);
        for (int j = 0; j < 4; ++j) {
            if (!((f >> j) & 1)) continue;
            const int k = 4 * lsrc + j;
            const float4* crow4 = (const float4*)(cb + (size_t)k * D_DIM);
            double a0 = 0.0, a1 = 0.0, a2 = 0.0, a3 = 0.0;
#pragma unroll
            for (int i = 0; i < 16; ++i) {
                float4 xa = xrow4[i * 64 + lane];
                float4 ca = crow4[i * 64 + lane];
                a0 += (double)xa.x * ca.x; a1 += (double)xa.y * ca.y;
                a2 += (double)xa.z * ca.z; a3 += (double)xa.w * ca.w;
            }
            double s = (a0 + a1) + (a2 + a3);
            for (int off = 32; off; off >>= 1) s += __shfl_xor(s, off);
            const double d2e = xxr + cc[k] - 2.0 * s;   // identical across lanes
            if (d2e > best) { best = d2e; bestk = k; }  // ascending k + strict >
        }
    }

    if (lane == 0) {
        out[IDX_OFF + row]  = (float)bestk;
        out[LOSS_OFF + row] = (float)(1.25 * best / (double)D_DIM);
        idxws[row] = bestk;
    }
}

// ---------------------------------------------------------------------------
// quant: pure streaming gather, wave-per-row. cb is L2/L3-resident (4 MB).
// ---------------------------------------------------------------------------
__global__ __launch_bounds__(256) void quant(const float* __restrict__ cb,
                                             const int* __restrict__ idxws,
                                             float* __restrict__ out) {
    const int lane = threadIdx.x & 63;
    const int row = blockIdx.x * 4 + (threadIdx.x >> 6);
    const int k = idxws[row];
    const float4* src = (const float4*)(cb + (size_t)k * D_DIM);
    float4* dst = (float4*)(out + (size_t)row * D_DIM);
#pragma unroll
    for (int i = 0; i < 16; ++i) dst[i * 64 + lane] = src[i * 64 + lane];
}

// ---------------------------------------------------------------------------
extern "C" void kernel_launch(void* const* d_in, const int* in_sizes, int n_in,
                              void* d_out, int out_size, void* d_ws, size_t ws_size,
                              hipStream_t stream) {
    const float* x  = (const float*)d_in[0];
    const float* cb = (const float*)d_in[1];
    float* out = (float*)d_out;

    float*          part = (float*)d_ws;
    unsigned short* cbh  = (unsigned short*)((char*)d_ws + PART_ELEMS * sizeof(float));
    double*         cc   = (double*)((char*)cbh + (size_t)K_CODES * D_DIM * sizeof(unsigned short));
    double*         xx   = cc + K_CODES;
    int*            idxws = (int*)(xx + B_ROWS);

    hipLaunchKernelGGL(prep,   dim3(1088),    dim3(256), 0, stream, x, cb, cbh, cc, xx, out);
    hipLaunchKernelGGL(gemm,   dim3(128, KS), dim3(256), 0, stream, x, cbh, part);
    hipLaunchKernelGGL(refine, dim3(1024),    dim3(256), 0, stream, x, cb, part, cc, xx, out, idxws);
    hipLaunchKernelGGL(quant,  dim3(1024),    dim3(256), 0, stream, cb, idxws, out);
}